// Round 1
// baseline (787.425 us; speedup 1.0000x reference)
//
#include <hip/hip_runtime.h>
#include <hip/hip_bf16.h>

typedef __hip_bfloat16 bf16;

#define P_CNT 16
#define J_CNT 23
#define VB    256          // verts per block
#define VPT   16           // verts per thread
#define WSTR  260          // sW row stride (words); %4==0 for b128 align, %32!=0 to spread staging banks

struct PosePtrs { const void* p[11]; };

__device__ const int   c_par[J_CNT]  = {-1,0,1,1,3,4,5,4,7,4,9,1,11,12,13,12,15,12,17,0,19,0,21};
__device__ const int   c_slot[J_CNT] = {0,-1,-1,1,2,3,-1,4,-1,5,-1,6,7,8,-1,9,-1,10,-1,-1,-1,-1,-1};
__device__ const float c_scale[11]   = {
    0.7853981633974483f, 1.5707963267948966f, 1.5707963267948966f, 0.7853981633974483f,
    0.7853981633974483f, 0.7853981633974483f, 1.5707963267948966f, 1.5707963267948966f,
    0.7853981633974483f, 0.7853981633974483f, 0.7853981633974483f};

template <bool BF>
__device__ __forceinline__ float ld(const void* p, long long i) {
    if (BF) return __bfloat162float(((const bf16*)p)[i]);
    return ((const float*)p)[i];
}
template <bool BF>
__device__ __forceinline__ void st(void* p, long long i, float v) {
    if (BF) ((bf16*)p)[i] = __float2bfloat16(v);
    else    ((float*)p)[i] = v;
}
__device__ __forceinline__ float bfu(unsigned short u) {
    union { unsigned short s; bf16 h; } c; c.s = u; return __bfloat162float(c.h);
}
__device__ __forceinline__ unsigned pack_bf(float a, float b) {
    union { bf16 h; unsigned short u; } A, B;
    A.h = __float2bfloat16(a); B.h = __float2bfloat16(b);
    return ((unsigned)B.u << 16) | (unsigned)A.u;
}

template <bool BF>
__device__ __forceinline__ void run(const void* __restrict__ verts,
                                    const void* __restrict__ joints,
                                    const void* __restrict__ weights,
                                    const void* __restrict__ disp,
                                    const void* __restrict__ rdis,
                                    const PosePtrs& pp,
                                    void* __restrict__ out, int V,
                                    float* sA, float* sW, float* sSh)
{
    const int t = threadIdx.x;
    const long long vb = (long long)blockIdx.x * VB;

    // ---- stage weights: transposed [j][row] with XOR swizzle on row ----
    {
        const long long totalF = (long long)V * J_CNT;
        const long long baseF  = vb * J_CNT;
#pragma unroll 1
        for (int e = t; e < VB * J_CNT; e += 256) {
            float val = (baseF + e < totalF) ? ld<BF>(weights, baseF + e) : 0.f;
            int r  = e / J_CNT;               // local row 0..255
            int j  = e - r * J_CNT;
            int wr = r ^ (((r >> 4) & 7) << 2);
            sW[j * WSTR + wr] = val;
        }
    }

    // ---- pose chain: thread p<16 builds global transforms G (rows [R|t]) ----
    if (t < P_CNT) {
        const int p = t;
        float* Gp = sA + p * (J_CNT * 12);
#pragma unroll 1
        for (int j = 0; j < J_CNT; ++j) {
            float rx = 0.f, ry = 0.f, rz = 0.f;
            int s = c_slot[j];
            if (s >= 0) {
                float sc = c_scale[s];
                rx = sc * tanhf(ld<BF>(pp.p[s], p * 3 + 0));
                ry = sc * tanhf(ld<BF>(pp.p[s], p * 3 + 1));
                rz = sc * tanhf(ld<BF>(pp.p[s], p * 3 + 2));
            }
            float ang = sqrtf(rx * rx + ry * ry + rz * rz + 1e-16f);
            float sn = sinf(ang), cs = cosf(ang);
            float C = 1.f - cs, inva = 1.f / ang;
            float x = rx * inva, y = ry * inva, z = rz * inva;
            float R00 = 1.f - C * (y * y + z * z), R01 = -sn * z + C * x * y, R02 = sn * y + C * x * z;
            float R10 = sn * z + C * x * y, R11 = 1.f - C * (x * x + z * z), R12 = -sn * x + C * y * z;
            float R20 = -sn * y + C * x * z, R21 = sn * x + C * y * z, R22 = 1.f - C * (x * x + y * y);
            int q = c_par[j];
            float t0 = ld<BF>(joints, j * 3 + 0);
            float t1 = ld<BF>(joints, j * 3 + 1);
            float t2 = ld<BF>(joints, j * 3 + 2);
            if (j == 0) {
                Gp[0] = R00; Gp[1] = R01; Gp[2]  = R02; Gp[3]  = t0;
                Gp[4] = R10; Gp[5] = R11; Gp[6]  = R12; Gp[7]  = t1;
                Gp[8] = R20; Gp[9] = R21; Gp[10] = R22; Gp[11] = t2;
            } else {
                t0 -= ld<BF>(joints, q * 3 + 0);
                t1 -= ld<BF>(joints, q * 3 + 1);
                t2 -= ld<BF>(joints, q * 3 + 2);
                const float* Gq = Gp + q * 12;
                float* Gj = Gp + j * 12;
#pragma unroll
                for (int i = 0; i < 3; ++i) {
                    float g0 = Gq[i * 4 + 0], g1 = Gq[i * 4 + 1];
                    float g2 = Gq[i * 4 + 2], g3 = Gq[i * 4 + 3];
                    Gj[i * 4 + 0] = g0 * R00 + g1 * R10 + g2 * R20;
                    Gj[i * 4 + 1] = g0 * R01 + g1 * R11 + g2 * R21;
                    Gj[i * 4 + 2] = g0 * R02 + g1 * R12 + g2 * R22;
                    Gj[i * 4 + 3] = g0 * t0 + g1 * t1 + g2 * t2 + g3;
                }
            }
        }
#pragma unroll
        for (int cc = 0; cc < 3; ++cc)
            sSh[t * 3 + cc] = ld<BF>(rdis, t * 3 + cc) + 3.f * tanhf(ld<BF>(disp, t * 3 + cc));
    }
    __syncthreads();

    // ---- convert G -> A in place (t' = t - R*jpos); block 0 writes out1 ----
    {
        const long long pv3 = (long long)P_CNT * V * 3;
        void* out1 = BF ? (void*)((bf16*)out + pv3) : (void*)((float*)out + pv3);
#pragma unroll 1
        for (int idx = t; idx < P_CNT * J_CNT; idx += 256) {
            int p = idx / J_CNT;
            int j = idx - p * J_CNT;
            float jx = ld<BF>(joints, j * 3 + 0);
            float jy = ld<BF>(joints, j * 3 + 1);
            float jz = ld<BF>(joints, j * 3 + 2);
            float* Ar = sA + (p * J_CNT + j) * 12;
#pragma unroll
            for (int i = 0; i < 3; ++i) {
                float g0 = Ar[i * 4 + 0], g1 = Ar[i * 4 + 1];
                float g2 = Ar[i * 4 + 2], g3 = Ar[i * 4 + 3];
                Ar[i * 4 + 3] = g3 - (g0 * jx + g1 * jy + g2 * jz);
                if (blockIdx.x == 0)
                    st<BF>(out1, (long long)(p * J_CNT + j) * 3 + i, g3 + sSh[p * 3 + i]);
            }
        }
    }

    // ---- per-thread vertex positions (16 consecutive verts) ----
    const int p = t >> 4, c = t & 15;
    const long long v0 = vb + (long long)c * VPT;
    const bool full = (v0 + VPT <= (long long)V);
    union F48 { float4 q[12]; float s[48]; };
    F48 P3;
    if (!BF && full) {
        const float4* vp = (const float4*)((const float*)verts + v0 * 3);
#pragma unroll
        for (int k = 0; k < 12; ++k) P3.q[k] = vp[k];
    } else if (BF && full) {
        const uint4* vp = (const uint4*)((const bf16*)verts + v0 * 3);
#pragma unroll
        for (int k = 0; k < 6; ++k) {
            uint4 u = vp[k];
            P3.s[k * 8 + 0] = bfu((unsigned short)(u.x & 0xffff));
            P3.s[k * 8 + 1] = bfu((unsigned short)(u.x >> 16));
            P3.s[k * 8 + 2] = bfu((unsigned short)(u.y & 0xffff));
            P3.s[k * 8 + 3] = bfu((unsigned short)(u.y >> 16));
            P3.s[k * 8 + 4] = bfu((unsigned short)(u.z & 0xffff));
            P3.s[k * 8 + 5] = bfu((unsigned short)(u.z >> 16));
            P3.s[k * 8 + 6] = bfu((unsigned short)(u.w & 0xffff));
            P3.s[k * 8 + 7] = bfu((unsigned short)(u.w >> 16));
        }
    } else {
        const long long lim = (long long)V * 3;
#pragma unroll
        for (int i = 0; i < 48; ++i) {
            long long gi = v0 * 3 + i;
            P3.s[i] = (gi < lim) ? ld<BF>(verts, gi) : 0.f;
        }
    }
    __syncthreads();

    // ---- main loop: out[p][v] = sum_j w[v][j] * (A[p][j] . [v,1]) ----
    float acc0[VPT], acc1[VPT], acc2[VPT];
#pragma unroll
    for (int v = 0; v < VPT; ++v) { acc0[v] = 0.f; acc1[v] = 0.f; acc2[v] = 0.f; }

    const int xm  = (c & 7) << 2;
    const int wq0 = (c * 16 + 0)  ^ xm;
    const int wq1 = (c * 16 + 4)  ^ xm;
    const int wq2 = (c * 16 + 8)  ^ xm;
    const int wq3 = (c * 16 + 12) ^ xm;
    const float* Ap = sA + p * (J_CNT * 12);

#pragma unroll 1
    for (int j = 0; j < J_CNT; ++j) {
        float4 a0 = *(const float4*)(Ap + j * 12 + 0);
        float4 a1 = *(const float4*)(Ap + j * 12 + 4);
        float4 a2 = *(const float4*)(Ap + j * 12 + 8);
        const float* Wj = sW + j * WSTR;
        union { float4 q[4]; float s[16]; } W;
        W.q[0] = *(const float4*)(Wj + wq0);
        W.q[1] = *(const float4*)(Wj + wq1);
        W.q[2] = *(const float4*)(Wj + wq2);
        W.q[3] = *(const float4*)(Wj + wq3);
#pragma unroll
        for (int v = 0; v < VPT; ++v) {
            float x = P3.s[v * 3 + 0], y = P3.s[v * 3 + 1], z = P3.s[v * 3 + 2];
            float wv = W.s[v];
            float d0 = fmaf(a0.z, z, fmaf(a0.y, y, fmaf(a0.x, x, a0.w)));
            float d1 = fmaf(a1.z, z, fmaf(a1.y, y, fmaf(a1.x, x, a1.w)));
            float d2 = fmaf(a2.z, z, fmaf(a2.y, y, fmaf(a2.x, x, a2.w)));
            acc0[v] = fmaf(wv, d0, acc0[v]);
            acc1[v] = fmaf(wv, d1, acc1[v]);
            acc2[v] = fmaf(wv, d2, acc2[v]);
        }
    }

    // ---- epilogue: add shift, store 48 contiguous elements ----
    const float shx = sSh[p * 3 + 0], shy = sSh[p * 3 + 1], shz = sSh[p * 3 + 2];
    F48 O;
#pragma unroll
    for (int v = 0; v < VPT; ++v) {
        O.s[v * 3 + 0] = acc0[v] + shx;
        O.s[v * 3 + 1] = acc1[v] + shy;
        O.s[v * 3 + 2] = acc2[v] + shz;
    }
    const long long obase = ((long long)p * V + v0) * 3;
    if (!BF) {
        if (full && (V % 4 == 0)) {
            float4* op = (float4*)((float*)out + obase);
#pragma unroll
            for (int k = 0; k < 12; ++k) op[k] = O.q[k];
        } else {
#pragma unroll
            for (int v = 0; v < VPT; ++v)
                if (v0 + v < (long long)V) {
                    ((float*)out)[obase + v * 3 + 0] = O.s[v * 3 + 0];
                    ((float*)out)[obase + v * 3 + 1] = O.s[v * 3 + 1];
                    ((float*)out)[obase + v * 3 + 2] = O.s[v * 3 + 2];
                }
        }
    } else {
        if (full && (V % 4 == 0)) {
            unsigned* op = (unsigned*)((bf16*)out + obase);  // 4B-aligned: obase even
#pragma unroll
            for (int k = 0; k < 24; ++k)
                op[k] = pack_bf(O.s[2 * k + 0], O.s[2 * k + 1]);
        } else {
#pragma unroll
            for (int v = 0; v < VPT; ++v)
                if (v0 + v < (long long)V) {
                    st<BF>(out, obase + v * 3 + 0, O.s[v * 3 + 0]);
                    st<BF>(out, obase + v * 3 + 1, O.s[v * 3 + 1]);
                    st<BF>(out, obase + v * 3 + 2, O.s[v * 3 + 2]);
                }
        }
    }
}

__global__ __launch_bounds__(256, 3) void lbs_all(
    const void* __restrict__ verts,
    const void* __restrict__ joints,
    const void* __restrict__ weights,
    const void* __restrict__ disp,
    const void* __restrict__ rdis,
    PosePtrs pp,
    void* __restrict__ out,
    int V)
{
    __shared__ float sA[P_CNT * J_CNT * 12];   // 17664 B: G chain, then A in place
    __shared__ float sW[J_CNT * WSTR];         // 23920 B: transposed+swizzled weights
    __shared__ float sSh[P_CNT * 3];
    __shared__ int   sFlag;

    if (threadIdx.x == 0) {
        // dtype detect via sum(weights row r)==1 invariant, rows 0..3
        const float* wf = (const float*)weights;
        const bf16*  wb = (const bf16*)weights;
        bool ok_f = true, ok_b = true;
        for (int r = 0; r < 4; ++r) {
            float sf = 0.f, sb = 0.f;
            for (int j = 0; j < J_CNT; ++j) {
                sf += wf[r * J_CNT + j];
                sb += __bfloat162float(wb[r * J_CNT + j]);
            }
            if (!(fabsf(sf - 1.f) < 0.02f)) ok_f = false;   // NaN-safe
            if (!(fabsf(sb - 1.f) < 0.10f)) ok_b = false;
        }
        sFlag = (!ok_f && ok_b) ? 1 : 0;
    }
    __syncthreads();
    if (sFlag)
        run<true >(verts, joints, weights, disp, rdis, pp, out, V, sA, sW, sSh);
    else
        run<false>(verts, joints, weights, disp, rdis, pp, out, V, sA, sW, sSh);
}

extern "C" void kernel_launch(void* const* d_in, const int* in_sizes, int n_in,
                              void* d_out, int out_size, void* d_ws, size_t ws_size,
                              hipStream_t stream) {
    const void* verts   = d_in[0];  // (1,V,3)
    const void* joints  = d_in[1];  // (1,23,3)
    const void* weights = d_in[2];  // (V,23)
    const void* disp    = d_in[3];  // (16,1,3)
    const void* rdis    = d_in[4];  // (16,3)
    PosePtrs pp;
    for (int i = 0; i < 11; ++i) pp.p[i] = d_in[5 + i];

    int V = in_sizes[0] / 3;  // 500000
    int G = (V + VB - 1) / VB;
    lbs_all<<<G, 256, 0, stream>>>(verts, joints, weights, disp, rdis, pp, d_out, V);
}

// Round 2
// 562.648 us; speedup vs baseline: 1.3995x; 1.3995x over previous
//
#include <hip/hip_runtime.h>
#include <hip/hip_bf16.h>

typedef __hip_bfloat16 bf16;

#define P_CNT 16
#define J_CNT 23
#define VB    128          // verts per block
#define VPT   8            // verts per thread (16 pose-groups x 16 cols = 256 thr)
#define WSTR  132          // sW row stride words: %4==0 (b128), %32==4 (bank spread)

struct PosePtrs { const void* p[11]; };

__device__ const int   c_par[J_CNT]  = {-1,0,1,1,3,4,5,4,7,4,9,1,11,12,13,12,15,12,17,0,19,0,21};
__device__ const int   c_slot[J_CNT] = {0,-1,-1,1,2,3,-1,4,-1,5,-1,6,7,8,-1,9,-1,10,-1,-1,-1,-1,-1};
__device__ const float c_scale[11]   = {
    0.7853981633974483f, 1.5707963267948966f, 1.5707963267948966f, 0.7853981633974483f,
    0.7853981633974483f, 0.7853981633974483f, 1.5707963267948966f, 1.5707963267948966f,
    0.7853981633974483f, 0.7853981633974483f, 0.7853981633974483f};

template <bool BF>
__device__ __forceinline__ float ld(const void* p, long long i) {
    if (BF) return __bfloat162float(((const bf16*)p)[i]);
    return ((const float*)p)[i];
}
template <bool BF>
__device__ __forceinline__ void st(void* p, long long i, float v) {
    if (BF) ((bf16*)p)[i] = __float2bfloat16(v);
    else    ((float*)p)[i] = v;
}
__device__ __forceinline__ float bflo(unsigned u) { return __uint_as_float(u << 16); }
__device__ __forceinline__ float bfhi(unsigned u) { return __uint_as_float(u & 0xffff0000u); }
__device__ __forceinline__ unsigned packbf(float a, float b) {
    bf16 ha = __float2bfloat16(a), hb = __float2bfloat16(b);
    unsigned short ua, ub;
    __builtin_memcpy(&ua, &ha, 2); __builtin_memcpy(&ub, &hb, 2);
    return ((unsigned)ub << 16) | (unsigned)ua;
}
__device__ __forceinline__ int swz(int r) { return r ^ (((r >> 5) & 1) << 2); }

template <bool BF>
__device__ __forceinline__ void run(const void* __restrict__ verts,
                                    const void* __restrict__ joints,
                                    const void* __restrict__ weights,
                                    const void* __restrict__ disp,
                                    const void* __restrict__ rdis,
                                    const PosePtrs& pp,
                                    void* __restrict__ out, int V,
                                    float* __restrict__ sA,
                                    float* __restrict__ sW,
                                    float* __restrict__ sSh)
{
    const int t = threadIdx.x;
    const int p = t >> 4, c = t & 15;
    const long long vb = (long long)blockIdx.x * VB;
    const long long v0 = vb + (long long)c * VPT;
    const bool valigned = ((V & 7) == 0);
    const bool full = ((v0 + VPT) <= (long long)V) && valigned;

    // ---- vertex loads, fully register-resident (plain arrays, static idx) ----
    float px[VPT], py[VPT], pz[VPT];
    if (full) {
        if (!BF) {
            const float4* vp = (const float4*)((const float*)verts + v0 * 3);
            float4 q0 = vp[0], q1 = vp[1], q2 = vp[2], q3 = vp[3], q4 = vp[4], q5 = vp[5];
            px[0] = q0.x; py[0] = q0.y; pz[0] = q0.z;
            px[1] = q0.w; py[1] = q1.x; pz[1] = q1.y;
            px[2] = q1.z; py[2] = q1.w; pz[2] = q2.x;
            px[3] = q2.y; py[3] = q2.z; pz[3] = q2.w;
            px[4] = q3.x; py[4] = q3.y; pz[4] = q3.z;
            px[5] = q3.w; py[5] = q4.x; pz[5] = q4.y;
            px[6] = q4.z; py[6] = q4.w; pz[6] = q5.x;
            px[7] = q5.y; py[7] = q5.z; pz[7] = q5.w;
        } else {
            const uint4* vp = (const uint4*)((const bf16*)verts + v0 * 3);
            uint4 u0 = vp[0], u1 = vp[1], u2 = vp[2];
            px[0] = bflo(u0.x); py[0] = bfhi(u0.x); pz[0] = bflo(u0.y);
            px[1] = bfhi(u0.y); py[1] = bflo(u0.z); pz[1] = bfhi(u0.z);
            px[2] = bflo(u0.w); py[2] = bfhi(u0.w); pz[2] = bflo(u1.x);
            px[3] = bfhi(u1.x); py[3] = bflo(u1.y); pz[3] = bfhi(u1.y);
            px[4] = bflo(u1.z); py[4] = bfhi(u1.z); pz[4] = bflo(u1.w);
            px[5] = bfhi(u1.w); py[5] = bflo(u2.x); pz[5] = bfhi(u2.x);
            px[6] = bflo(u2.y); py[6] = bfhi(u2.y); pz[6] = bflo(u2.z);
            px[7] = bfhi(u2.z); py[7] = bflo(u2.w); pz[7] = bfhi(u2.w);
        }
    } else {
#pragma unroll
        for (int v = 0; v < VPT; ++v) {
            bool ok = (v0 + v) < (long long)V;
            px[v] = ok ? ld<BF>(verts, (v0 + v) * 3 + 0) : 0.f;
            py[v] = ok ? ld<BF>(verts, (v0 + v) * 3 + 1) : 0.f;
            pz[v] = ok ? ld<BF>(verts, (v0 + v) * 3 + 2) : 0.f;
        }
    }

    // ---- stage weights -> LDS, transposed [j][swz(row)] ----
    {
        const long long baseF  = vb * J_CNT;
        const long long totalF = (long long)V * J_CNT;
        if (baseF + VB * J_CNT <= totalF) {
            if (!BF) {
                const float4* wp = (const float4*)((const float*)weights + baseF);
#pragma unroll 1
                for (int idx = t; idx < (VB * J_CNT) / 4; idx += 256) {   // 736
                    float4 w4 = wp[idx];
                    int e = idx * 4;
                    { int r = (e+0)/J_CNT, j = (e+0)-r*J_CNT; sW[j*WSTR + swz(r)] = w4.x; }
                    { int r = (e+1)/J_CNT, j = (e+1)-r*J_CNT; sW[j*WSTR + swz(r)] = w4.y; }
                    { int r = (e+2)/J_CNT, j = (e+2)-r*J_CNT; sW[j*WSTR + swz(r)] = w4.z; }
                    { int r = (e+3)/J_CNT, j = (e+3)-r*J_CNT; sW[j*WSTR + swz(r)] = w4.w; }
                }
            } else {
                const uint4* wp = (const uint4*)((const bf16*)weights + baseF);
#pragma unroll 1
                for (int idx = t; idx < (VB * J_CNT) / 8; idx += 256) {   // 368
                    uint4 u = wp[idx];
                    int e = idx * 8;
                    float f0 = bflo(u.x), f1 = bfhi(u.x), f2 = bflo(u.y), f3 = bfhi(u.y);
                    float f4 = bflo(u.z), f5 = bfhi(u.z), f6 = bflo(u.w), f7 = bfhi(u.w);
                    { int r = (e+0)/J_CNT, j = (e+0)-r*J_CNT; sW[j*WSTR + swz(r)] = f0; }
                    { int r = (e+1)/J_CNT, j = (e+1)-r*J_CNT; sW[j*WSTR + swz(r)] = f1; }
                    { int r = (e+2)/J_CNT, j = (e+2)-r*J_CNT; sW[j*WSTR + swz(r)] = f2; }
                    { int r = (e+3)/J_CNT, j = (e+3)-r*J_CNT; sW[j*WSTR + swz(r)] = f3; }
                    { int r = (e+4)/J_CNT, j = (e+4)-r*J_CNT; sW[j*WSTR + swz(r)] = f4; }
                    { int r = (e+5)/J_CNT, j = (e+5)-r*J_CNT; sW[j*WSTR + swz(r)] = f5; }
                    { int r = (e+6)/J_CNT, j = (e+6)-r*J_CNT; sW[j*WSTR + swz(r)] = f6; }
                    { int r = (e+7)/J_CNT, j = (e+7)-r*J_CNT; sW[j*WSTR + swz(r)] = f7; }
                }
            }
        } else {
#pragma unroll 1
            for (int e = t; e < VB * J_CNT; e += 256) {
                float val = (baseF + e < totalF) ? ld<BF>(weights, baseF + e) : 0.f;
                int r = e / J_CNT, j = e - r * J_CNT;
                sW[j * WSTR + swz(r)] = val;
            }
        }
    }

    // ---- phase 1: per-(p,j) local transforms T=[R|t] by ALL threads ----
#pragma unroll 1
    for (int idx = t; idx < P_CNT * J_CNT; idx += 256) {
        int pq = idx / J_CNT, j = idx - pq * J_CNT;
        float rx = 0.f, ry = 0.f, rz = 0.f;
        int s = c_slot[j];
        if (s >= 0) {
            float sc = c_scale[s];
            rx = sc * tanhf(ld<BF>(pp.p[s], pq * 3 + 0));
            ry = sc * tanhf(ld<BF>(pp.p[s], pq * 3 + 1));
            rz = sc * tanhf(ld<BF>(pp.p[s], pq * 3 + 2));
        }
        float ang = sqrtf(rx * rx + ry * ry + rz * rz + 1e-16f);
        float sn = sinf(ang), cs = cosf(ang);
        float C = 1.f - cs, inva = 1.f / ang;
        float x = rx * inva, y = ry * inva, z = rz * inva;
        float t0 = ld<BF>(joints, j * 3 + 0);
        float t1 = ld<BF>(joints, j * 3 + 1);
        float t2 = ld<BF>(joints, j * 3 + 2);
        if (j != 0) {
            int q = c_par[j];
            t0 -= ld<BF>(joints, q * 3 + 0);
            t1 -= ld<BF>(joints, q * 3 + 1);
            t2 -= ld<BF>(joints, q * 3 + 2);
        }
        float* Ar = sA + idx * 12;
        Ar[0]  = 1.f - C * (y * y + z * z); Ar[1]  = -sn * z + C * x * y;       Ar[2]  = sn * y + C * x * z;       Ar[3]  = t0;
        Ar[4]  = sn * z + C * x * y;        Ar[5]  = 1.f - C * (x * x + z * z); Ar[6]  = -sn * x + C * y * z;      Ar[7]  = t1;
        Ar[8]  = -sn * y + C * x * z;       Ar[9]  = sn * x + C * y * z;        Ar[10] = 1.f - C * (x * x + y * y);Ar[11] = t2;
    }
    if (t < P_CNT) {
#pragma unroll
        for (int cc = 0; cc < 3; ++cc)
            sSh[t * 3 + cc] = ld<BF>(rdis, t * 3 + cc) + 3.f * tanhf(ld<BF>(disp, t * 3 + cc));
    }
    __syncthreads();

    // ---- phase 2: chain composition in-place (16 lanes, own pose only) ----
    if (t < P_CNT) {
        float* Gp = sA + t * (J_CNT * 12);
#pragma unroll 1
        for (int j = 1; j < J_CNT; ++j) {
            const float* Gq = Gp + c_par[j] * 12;
            float* Tj = Gp + j * 12;
            float4 gq0 = *(const float4*)(Gq + 0);
            float4 gq1 = *(const float4*)(Gq + 4);
            float4 gq2 = *(const float4*)(Gq + 8);
            float4 r0 = *(const float4*)(Tj + 0);
            float4 r1 = *(const float4*)(Tj + 4);
            float4 r2 = *(const float4*)(Tj + 8);
            float4 o0, o1, o2;
            o0.x = gq0.x*r0.x + gq0.y*r1.x + gq0.z*r2.x;
            o0.y = gq0.x*r0.y + gq0.y*r1.y + gq0.z*r2.y;
            o0.z = gq0.x*r0.z + gq0.y*r1.z + gq0.z*r2.z;
            o0.w = gq0.x*r0.w + gq0.y*r1.w + gq0.z*r2.w + gq0.w;
            o1.x = gq1.x*r0.x + gq1.y*r1.x + gq1.z*r2.x;
            o1.y = gq1.x*r0.y + gq1.y*r1.y + gq1.z*r2.y;
            o1.z = gq1.x*r0.z + gq1.y*r1.z + gq1.z*r2.z;
            o1.w = gq1.x*r0.w + gq1.y*r1.w + gq1.z*r2.w + gq1.w;
            o2.x = gq2.x*r0.x + gq2.y*r1.x + gq2.z*r2.x;
            o2.y = gq2.x*r0.y + gq2.y*r1.y + gq2.z*r2.y;
            o2.z = gq2.x*r0.z + gq2.y*r1.z + gq2.z*r2.z;
            o2.w = gq2.x*r0.w + gq2.y*r1.w + gq2.z*r2.w + gq2.w;
            *(float4*)(Tj + 0) = o0;
            *(float4*)(Tj + 4) = o1;
            *(float4*)(Tj + 8) = o2;
        }
    }
    __syncthreads();

    // ---- phase 3: G -> A in place (t' = t - R*j); block 0 writes out1 ----
    {
        const long long pv3 = (long long)P_CNT * V * 3;
#pragma unroll 1
        for (int idx = t; idx < P_CNT * J_CNT; idx += 256) {
            int pq = idx / J_CNT, j = idx - pq * J_CNT;
            float jx = ld<BF>(joints, j * 3 + 0);
            float jy = ld<BF>(joints, j * 3 + 1);
            float jz = ld<BF>(joints, j * 3 + 2);
            float* Ar = sA + idx * 12;
            float g03 = Ar[3], g13 = Ar[7], g23 = Ar[11];
            Ar[3]  = g03 - (Ar[0] * jx + Ar[1] * jy + Ar[2]  * jz);
            Ar[7]  = g13 - (Ar[4] * jx + Ar[5] * jy + Ar[6]  * jz);
            Ar[11] = g23 - (Ar[8] * jx + Ar[9] * jy + Ar[10] * jz);
            if (blockIdx.x == 0) {
                void* out1 = BF ? (void*)((bf16*)out + pv3) : (void*)((float*)out + pv3);
                st<BF>(out1, (long long)idx * 3 + 0, g03 + sSh[pq * 3 + 0]);
                st<BF>(out1, (long long)idx * 3 + 1, g13 + sSh[pq * 3 + 1]);
                st<BF>(out1, (long long)idx * 3 + 2, g23 + sSh[pq * 3 + 2]);
            }
        }
    }
    __syncthreads();

    // ---- main loop ----
    float ax[VPT], ay[VPT], az[VPT];
#pragma unroll
    for (int v = 0; v < VPT; ++v) { ax[v] = 0.f; ay[v] = 0.f; az[v] = 0.f; }

    const int s4 = ((c >> 2) & 1) << 2;
    const float* WA = sW + (c << 3) + s4;        // rows v0..v0+3 (in order)
    const float* WB = sW + (c << 3) + 4 - s4;    // rows v0+4..v0+7 (in order)
    const float* Ap = sA + p * (J_CNT * 12);

#define STEP(vv, wv) { \
        float d0 = fmaf(a0.x, px[vv], fmaf(a0.y, py[vv], fmaf(a0.z, pz[vv], a0.w))); \
        float d1 = fmaf(a1.x, px[vv], fmaf(a1.y, py[vv], fmaf(a1.z, pz[vv], a1.w))); \
        float d2 = fmaf(a2.x, px[vv], fmaf(a2.y, py[vv], fmaf(a2.z, pz[vv], a2.w))); \
        ax[vv] = fmaf(wv, d0, ax[vv]); \
        ay[vv] = fmaf(wv, d1, ay[vv]); \
        az[vv] = fmaf(wv, d2, az[vv]); }

#pragma unroll 2
    for (int j = 0; j < J_CNT; ++j) {
        float4 a0 = *(const float4*)(Ap + j * 12 + 0);
        float4 a1 = *(const float4*)(Ap + j * 12 + 4);
        float4 a2 = *(const float4*)(Ap + j * 12 + 8);
        float4 wA = *(const float4*)(WA + j * WSTR);
        float4 wB = *(const float4*)(WB + j * WSTR);
        STEP(0, wA.x) STEP(1, wA.y) STEP(2, wA.z) STEP(3, wA.w)
        STEP(4, wB.x) STEP(5, wB.y) STEP(6, wB.z) STEP(7, wB.w)
    }
#undef STEP

    // ---- epilogue ----
    const float shx = sSh[p * 3 + 0], shy = sSh[p * 3 + 1], shz = sSh[p * 3 + 2];
#pragma unroll
    for (int v = 0; v < VPT; ++v) { ax[v] += shx; ay[v] += shy; az[v] += shz; }

    const long long obase = ((long long)p * V + v0) * 3;
    if (!BF) {
        if (full) {
            float4* op = (float4*)((float*)out + obase);
            op[0] = make_float4(ax[0], ay[0], az[0], ax[1]);
            op[1] = make_float4(ay[1], az[1], ax[2], ay[2]);
            op[2] = make_float4(az[2], ax[3], ay[3], az[3]);
            op[3] = make_float4(ax[4], ay[4], az[4], ax[5]);
            op[4] = make_float4(ay[5], az[5], ax[6], ay[6]);
            op[5] = make_float4(az[6], ax[7], ay[7], az[7]);
        } else {
#pragma unroll
            for (int v = 0; v < VPT; ++v)
                if (v0 + v < (long long)V) {
                    ((float*)out)[obase + v * 3 + 0] = ax[v];
                    ((float*)out)[obase + v * 3 + 1] = ay[v];
                    ((float*)out)[obase + v * 3 + 2] = az[v];
                }
        }
    } else {
        if (full) {
            uint4* op = (uint4*)((bf16*)out + obase);
            op[0] = make_uint4(packbf(ax[0], ay[0]), packbf(az[0], ax[1]),
                               packbf(ay[1], az[1]), packbf(ax[2], ay[2]));
            op[1] = make_uint4(packbf(az[2], ax[3]), packbf(ay[3], az[3]),
                               packbf(ax[4], ay[4]), packbf(az[4], ax[5]));
            op[2] = make_uint4(packbf(ay[5], az[5]), packbf(ax[6], ay[6]),
                               packbf(az[6], ax[7]), packbf(ay[7], az[7]));
        } else {
#pragma unroll
            for (int v = 0; v < VPT; ++v)
                if (v0 + v < (long long)V) {
                    st<BF>(out, obase + v * 3 + 0, ax[v]);
                    st<BF>(out, obase + v * 3 + 1, ay[v]);
                    st<BF>(out, obase + v * 3 + 2, az[v]);
                }
        }
    }
}

__global__ __launch_bounds__(256, 4) void lbs_all(
    const void* __restrict__ verts,
    const void* __restrict__ joints,
    const void* __restrict__ weights,
    const void* __restrict__ disp,
    const void* __restrict__ rdis,
    PosePtrs pp,
    void* __restrict__ out,
    int V)
{
    __shared__ __align__(16) float sA[P_CNT * J_CNT * 12];   // 17664 B
    __shared__ __align__(16) float sW[J_CNT * WSTR];         // 12144 B
    __shared__ float sSh[P_CNT * 3];
    __shared__ int   sFlag;

    if (threadIdx.x == 0) {
        const float* wf = (const float*)weights;
        const bf16*  wb = (const bf16*)weights;
        bool ok_f = true, ok_b = true;
        for (int r = 0; r < 4; ++r) {
            float sf = 0.f, sb = 0.f;
            for (int j = 0; j < J_CNT; ++j) {
                sf += wf[r * J_CNT + j];
                sb += __bfloat162float(wb[r * J_CNT + j]);
            }
            if (!(fabsf(sf - 1.f) < 0.02f)) ok_f = false;   // NaN-safe
            if (!(fabsf(sb - 1.f) < 0.10f)) ok_b = false;
        }
        sFlag = (!ok_f && ok_b) ? 1 : 0;
    }
    __syncthreads();
    if (sFlag)
        run<true >(verts, joints, weights, disp, rdis, pp, out, V, sA, sW, sSh);
    else
        run<false>(verts, joints, weights, disp, rdis, pp, out, V, sA, sW, sSh);
}

extern "C" void kernel_launch(void* const* d_in, const int* in_sizes, int n_in,
                              void* d_out, int out_size, void* d_ws, size_t ws_size,
                              hipStream_t stream) {
    const void* verts   = d_in[0];  // (1,V,3)
    const void* joints  = d_in[1];  // (1,23,3)
    const void* weights = d_in[2];  // (V,23)
    const void* disp    = d_in[3];  // (16,1,3)
    const void* rdis    = d_in[4];  // (16,3)
    PosePtrs pp;
    for (int i = 0; i < 11; ++i) pp.p[i] = d_in[5 + i];

    int V = in_sizes[0] / 3;  // 500000
    int G = (V + VB - 1) / VB;
    lbs_all<<<G, 256, 0, stream>>>(verts, joints, weights, disp, rdis, pp, d_out, V);
}

// Round 4
// 287.989 us; speedup vs baseline: 2.7342x; 1.9537x over previous
//
#include <hip/hip_runtime.h>
#include <hip/hip_bf16.h>

typedef __hip_bfloat16 bf16;

#define P_CNT 16
#define J_CNT 23
#define VB    128          // verts per block
#define VPT   8            // verts per thread (16 pose-groups x 16 cols = 256 thr)
#define WSTR  132          // sW row stride words: %4==0 (b128), %32==4 (bank spread)

struct PosePtrs { const void* p[11]; };

__device__ const int   c_par[J_CNT]  = {-1,0,1,1,3,4,5,4,7,4,9,1,11,12,13,12,15,12,17,0,19,0,21};
__device__ const int   c_slot[J_CNT] = {0,-1,-1,1,2,3,-1,4,-1,5,-1,6,7,8,-1,9,-1,10,-1,-1,-1,-1,-1};
__device__ const float c_scale[11]   = {
    0.7853981633974483f, 1.5707963267948966f, 1.5707963267948966f, 0.7853981633974483f,
    0.7853981633974483f, 0.7853981633974483f, 1.5707963267948966f, 1.5707963267948966f,
    0.7853981633974483f, 0.7853981633974483f, 0.7853981633974483f};

template <bool BF>
__device__ __forceinline__ float ld(const void* p, long long i) {
    if (BF) return __bfloat162float(((const bf16*)p)[i]);
    return ((const float*)p)[i];
}
template <bool BF>
__device__ __forceinline__ void st(void* p, long long i, float v) {
    if (BF) ((bf16*)p)[i] = __float2bfloat16(v);
    else    ((float*)p)[i] = v;
}
__device__ __forceinline__ float bflo(unsigned u) { return __uint_as_float(u << 16); }
__device__ __forceinline__ float bfhi(unsigned u) { return __uint_as_float(u & 0xffff0000u); }
__device__ __forceinline__ unsigned packbf(float a, float b) {
    bf16 ha = __float2bfloat16(a), hb = __float2bfloat16(b);
    unsigned short ua, ub;
    __builtin_memcpy(&ua, &ha, 2); __builtin_memcpy(&ub, &hb, 2);
    return ((unsigned)ub << 16) | (unsigned)ua;
}
__device__ __forceinline__ int swz(int r) { return r ^ (((r >> 5) & 1) << 2); }

template <bool BF>
__device__ __forceinline__ void run(const void* __restrict__ verts,
                                    const void* __restrict__ joints,
                                    const void* __restrict__ weights,
                                    const void* __restrict__ disp,
                                    const void* __restrict__ rdis,
                                    const PosePtrs pp,
                                    void* __restrict__ out, int V,
                                    float* __restrict__ sA,
                                    float* __restrict__ sW,
                                    float* __restrict__ sPose,
                                    float* __restrict__ sSh)
{
    const int t = threadIdx.x;
    const int p = t >> 4, c = t & 15;
    const long long vb = (long long)blockIdx.x * VB;
    const long long v0 = vb + (long long)c * VPT;
    const bool valigned = ((V & 7) == 0);
    const bool full = ((v0 + VPT) <= (long long)V) && valigned;

    // ---- vertex loads, fully register-resident (plain arrays, static idx) ----
    float px[VPT], py[VPT], pz[VPT];
    if (full) {
        if (!BF) {
            const float4* vp = (const float4*)((const float*)verts + v0 * 3);
            float4 q0 = vp[0], q1 = vp[1], q2 = vp[2], q3 = vp[3], q4 = vp[4], q5 = vp[5];
            px[0] = q0.x; py[0] = q0.y; pz[0] = q0.z;
            px[1] = q0.w; py[1] = q1.x; pz[1] = q1.y;
            px[2] = q1.z; py[2] = q1.w; pz[2] = q2.x;
            px[3] = q2.y; py[3] = q2.z; pz[3] = q2.w;
            px[4] = q3.x; py[4] = q3.y; pz[4] = q3.z;
            px[5] = q3.w; py[5] = q4.x; pz[5] = q4.y;
            px[6] = q4.z; py[6] = q4.w; pz[6] = q5.x;
            px[7] = q5.y; py[7] = q5.z; pz[7] = q5.w;
        } else {
            const uint4* vp = (const uint4*)((const bf16*)verts + v0 * 3);
            uint4 u0 = vp[0], u1 = vp[1], u2 = vp[2];
            px[0] = bflo(u0.x); py[0] = bfhi(u0.x); pz[0] = bflo(u0.y);
            px[1] = bfhi(u0.y); py[1] = bflo(u0.z); pz[1] = bfhi(u0.z);
            px[2] = bflo(u0.w); py[2] = bfhi(u0.w); pz[2] = bflo(u1.x);
            px[3] = bfhi(u1.x); py[3] = bflo(u1.y); pz[3] = bfhi(u1.y);
            px[4] = bflo(u1.z); py[4] = bfhi(u1.z); pz[4] = bflo(u1.w);
            px[5] = bfhi(u1.w); py[5] = bflo(u2.x); pz[5] = bfhi(u2.x);
            px[6] = bflo(u2.y); py[6] = bfhi(u2.y); pz[6] = bflo(u2.z);
            px[7] = bfhi(u2.z); py[7] = bflo(u2.w); pz[7] = bfhi(u2.w);
        }
    } else {
#pragma unroll
        for (int v = 0; v < VPT; ++v) {
            bool ok = (v0 + v) < (long long)V;
            px[v] = ok ? ld<BF>(verts, (v0 + v) * 3 + 0) : 0.f;
            py[v] = ok ? ld<BF>(verts, (v0 + v) * 3 + 1) : 0.f;
            pz[v] = ok ? ld<BF>(verts, (v0 + v) * 3 + 2) : 0.f;
        }
    }

    // ---- stage pose params -> LDS (slot index is COMPILE-TIME: no kernarg
    //      dynamic indexing -> no scratch alloca) ----
#pragma unroll
    for (int s = 0; s < 11; ++s) {
        if (t < P_CNT * 3) sPose[s * (P_CNT * 3) + t] = ld<BF>(pp.p[s], t);
    }

    // ---- stage weights -> LDS, transposed [j][swz(row)] ----
    {
        const long long baseF  = vb * J_CNT;
        const long long totalF = (long long)V * J_CNT;
        if (baseF + VB * J_CNT <= totalF) {
            if (!BF) {
                const float4* wp = (const float4*)((const float*)weights + baseF);
#pragma unroll 1
                for (int idx = t; idx < (VB * J_CNT) / 4; idx += 256) {   // 736
                    float4 w4 = wp[idx];
                    int e = idx * 4;
                    { int r = (e+0)/J_CNT, j = (e+0)-r*J_CNT; sW[j*WSTR + swz(r)] = w4.x; }
                    { int r = (e+1)/J_CNT, j = (e+1)-r*J_CNT; sW[j*WSTR + swz(r)] = w4.y; }
                    { int r = (e+2)/J_CNT, j = (e+2)-r*J_CNT; sW[j*WSTR + swz(r)] = w4.z; }
                    { int r = (e+3)/J_CNT, j = (e+3)-r*J_CNT; sW[j*WSTR + swz(r)] = w4.w; }
                }
            } else {
                const uint4* wp = (const uint4*)((const bf16*)weights + baseF);
#pragma unroll 1
                for (int idx = t; idx < (VB * J_CNT) / 8; idx += 256) {   // 368
                    uint4 u = wp[idx];
                    int e = idx * 8;
                    float f0 = bflo(u.x), f1 = bfhi(u.x), f2 = bflo(u.y), f3 = bfhi(u.y);
                    float f4 = bflo(u.z), f5 = bfhi(u.z), f6 = bflo(u.w), f7 = bfhi(u.w);
                    { int r = (e+0)/J_CNT, j = (e+0)-r*J_CNT; sW[j*WSTR + swz(r)] = f0; }
                    { int r = (e+1)/J_CNT, j = (e+1)-r*J_CNT; sW[j*WSTR + swz(r)] = f1; }
                    { int r = (e+2)/J_CNT, j = (e+2)-r*J_CNT; sW[j*WSTR + swz(r)] = f2; }
                    { int r = (e+3)/J_CNT, j = (e+3)-r*J_CNT; sW[j*WSTR + swz(r)] = f3; }
                    { int r = (e+4)/J_CNT, j = (e+4)-r*J_CNT; sW[j*WSTR + swz(r)] = f4; }
                    { int r = (e+5)/J_CNT, j = (e+5)-r*J_CNT; sW[j*WSTR + swz(r)] = f5; }
                    { int r = (e+6)/J_CNT, j = (e+6)-r*J_CNT; sW[j*WSTR + swz(r)] = f6; }
                    { int r = (e+7)/J_CNT, j = (e+7)-r*J_CNT; sW[j*WSTR + swz(r)] = f7; }
                }
            }
        } else {
#pragma unroll 1
            for (int e = t; e < VB * J_CNT; e += 256) {
                float val = (baseF + e < totalF) ? ld<BF>(weights, baseF + e) : 0.f;
                int r = e / J_CNT, j = e - r * J_CNT;
                sW[j * WSTR + swz(r)] = val;
            }
        }
    }
    __syncthreads();   // sPose ready

    // ---- phase 1: per-(p,j) local transforms T=[R|t] by ALL threads ----
#pragma unroll 1
    for (int idx = t; idx < P_CNT * J_CNT; idx += 256) {
        int pq = idx / J_CNT, j = idx - pq * J_CNT;
        float rx = 0.f, ry = 0.f, rz = 0.f;
        int s = c_slot[j];
        if (s >= 0) {
            float sc = c_scale[s];
            rx = sc * tanhf(sPose[s * (P_CNT * 3) + pq * 3 + 0]);
            ry = sc * tanhf(sPose[s * (P_CNT * 3) + pq * 3 + 1]);
            rz = sc * tanhf(sPose[s * (P_CNT * 3) + pq * 3 + 2]);
        }
        float ang = sqrtf(rx * rx + ry * ry + rz * rz + 1e-16f);
        float sn = sinf(ang), cs = cosf(ang);
        float C = 1.f - cs, inva = 1.f / ang;
        float x = rx * inva, y = ry * inva, z = rz * inva;
        float t0 = ld<BF>(joints, j * 3 + 0);
        float t1 = ld<BF>(joints, j * 3 + 1);
        float t2 = ld<BF>(joints, j * 3 + 2);
        if (j != 0) {
            int q = c_par[j];
            t0 -= ld<BF>(joints, q * 3 + 0);
            t1 -= ld<BF>(joints, q * 3 + 1);
            t2 -= ld<BF>(joints, q * 3 + 2);
        }
        float* Ar = sA + idx * 12;
        Ar[0]  = 1.f - C * (y * y + z * z); Ar[1]  = -sn * z + C * x * y;       Ar[2]  = sn * y + C * x * z;       Ar[3]  = t0;
        Ar[4]  = sn * z + C * x * y;        Ar[5]  = 1.f - C * (x * x + z * z); Ar[6]  = -sn * x + C * y * z;      Ar[7]  = t1;
        Ar[8]  = -sn * y + C * x * z;       Ar[9]  = sn * x + C * y * z;        Ar[10] = 1.f - C * (x * x + y * y);Ar[11] = t2;
    }
    if (t < P_CNT) {
#pragma unroll
        for (int cc = 0; cc < 3; ++cc)
            sSh[t * 3 + cc] = ld<BF>(rdis, t * 3 + cc) + 3.f * tanhf(ld<BF>(disp, t * 3 + cc));
    }
    __syncthreads();

    // ---- phase 2: chain composition in-place (16 lanes, own pose only) ----
    if (t < P_CNT) {
        float* Gp = sA + t * (J_CNT * 12);
#pragma unroll 1
        for (int j = 1; j < J_CNT; ++j) {
            const float* Gq = Gp + c_par[j] * 12;
            float* Tj = Gp + j * 12;
            float4 gq0 = *(const float4*)(Gq + 0);
            float4 gq1 = *(const float4*)(Gq + 4);
            float4 gq2 = *(const float4*)(Gq + 8);
            float4 r0 = *(const float4*)(Tj + 0);
            float4 r1 = *(const float4*)(Tj + 4);
            float4 r2 = *(const float4*)(Tj + 8);
            float4 o0, o1, o2;
            o0.x = gq0.x*r0.x + gq0.y*r1.x + gq0.z*r2.x;
            o0.y = gq0.x*r0.y + gq0.y*r1.y + gq0.z*r2.y;
            o0.z = gq0.x*r0.z + gq0.y*r1.z + gq0.z*r2.z;
            o0.w = gq0.x*r0.w + gq0.y*r1.w + gq0.z*r2.w + gq0.w;
            o1.x = gq1.x*r0.x + gq1.y*r1.x + gq1.z*r2.x;
            o1.y = gq1.x*r0.y + gq1.y*r1.y + gq1.z*r2.y;
            o1.z = gq1.x*r0.z + gq1.y*r1.z + gq1.z*r2.z;
            o1.w = gq1.x*r0.w + gq1.y*r1.w + gq1.z*r2.w + gq1.w;
            o2.x = gq2.x*r0.x + gq2.y*r1.x + gq2.z*r2.x;
            o2.y = gq2.x*r0.y + gq2.y*r1.y + gq2.z*r2.y;
            o2.z = gq2.x*r0.z + gq2.y*r1.z + gq2.z*r2.z;
            o2.w = gq2.x*r0.w + gq2.y*r1.w + gq2.z*r2.w + gq2.w;
            *(float4*)(Tj + 0) = o0;
            *(float4*)(Tj + 4) = o1;
            *(float4*)(Tj + 8) = o2;
        }
    }
    __syncthreads();

    // ---- phase 3: G -> A in place (t' = t - R*j); block 0 writes out1 ----
    {
        const long long pv3 = (long long)P_CNT * V * 3;
#pragma unroll 1
        for (int idx = t; idx < P_CNT * J_CNT; idx += 256) {
            int pq = idx / J_CNT, j = idx - pq * J_CNT;
            float jx = ld<BF>(joints, j * 3 + 0);
            float jy = ld<BF>(joints, j * 3 + 1);
            float jz = ld<BF>(joints, j * 3 + 2);
            float* Ar = sA + idx * 12;
            float g03 = Ar[3], g13 = Ar[7], g23 = Ar[11];
            Ar[3]  = g03 - (Ar[0] * jx + Ar[1] * jy + Ar[2]  * jz);
            Ar[7]  = g13 - (Ar[4] * jx + Ar[5] * jy + Ar[6]  * jz);
            Ar[11] = g23 - (Ar[8] * jx + Ar[9] * jy + Ar[10] * jz);
            if (blockIdx.x == 0) {
                void* out1 = BF ? (void*)((bf16*)out + pv3) : (void*)((float*)out + pv3);
                st<BF>(out1, (long long)idx * 3 + 0, g03 + sSh[pq * 3 + 0]);
                st<BF>(out1, (long long)idx * 3 + 1, g13 + sSh[pq * 3 + 1]);
                st<BF>(out1, (long long)idx * 3 + 2, g23 + sSh[pq * 3 + 2]);
            }
        }
    }
    __syncthreads();

    // ---- main loop ----
    float ax[VPT], ay[VPT], az[VPT];
#pragma unroll
    for (int v = 0; v < VPT; ++v) { ax[v] = 0.f; ay[v] = 0.f; az[v] = 0.f; }

    const int s4 = ((c >> 2) & 1) << 2;
    const float* WA = sW + (c << 3) + s4;        // rows v0..v0+3 (in order)
    const float* WB = sW + (c << 3) + 4 - s4;    // rows v0+4..v0+7 (in order)
    const float* Ap = sA + p * (J_CNT * 12);

#define STEP(vv, wv) { \
        float d0 = fmaf(a0.x, px[vv], fmaf(a0.y, py[vv], fmaf(a0.z, pz[vv], a0.w))); \
        float d1 = fmaf(a1.x, px[vv], fmaf(a1.y, py[vv], fmaf(a1.z, pz[vv], a1.w))); \
        float d2 = fmaf(a2.x, px[vv], fmaf(a2.y, py[vv], fmaf(a2.z, pz[vv], a2.w))); \
        ax[vv] = fmaf(wv, d0, ax[vv]); \
        ay[vv] = fmaf(wv, d1, ay[vv]); \
        az[vv] = fmaf(wv, d2, az[vv]); }

#pragma unroll 2
    for (int j = 0; j < J_CNT; ++j) {
        float4 a0 = *(const float4*)(Ap + j * 12 + 0);
        float4 a1 = *(const float4*)(Ap + j * 12 + 4);
        float4 a2 = *(const float4*)(Ap + j * 12 + 8);
        float4 wA = *(const float4*)(WA + j * WSTR);
        float4 wB = *(const float4*)(WB + j * WSTR);
        STEP(0, wA.x) STEP(1, wA.y) STEP(2, wA.z) STEP(3, wA.w)
        STEP(4, wB.x) STEP(5, wB.y) STEP(6, wB.z) STEP(7, wB.w)
    }
#undef STEP

    // ---- epilogue ----
    const float shx = sSh[p * 3 + 0], shy = sSh[p * 3 + 1], shz = sSh[p * 3 + 2];
#pragma unroll
    for (int v = 0; v < VPT; ++v) { ax[v] += shx; ay[v] += shy; az[v] += shz; }

    const long long obase = ((long long)p * V + v0) * 3;
    if (!BF) {
        if (full) {
            float4* op = (float4*)((float*)out + obase);
            op[0] = make_float4(ax[0], ay[0], az[0], ax[1]);
            op[1] = make_float4(ay[1], az[1], ax[2], ay[2]);
            op[2] = make_float4(az[2], ax[3], ay[3], az[3]);
            op[3] = make_float4(ax[4], ay[4], az[4], ax[5]);
            op[4] = make_float4(ay[5], az[5], ax[6], ay[6]);
            op[5] = make_float4(az[6], ax[7], ay[7], az[7]);
        } else {
#pragma unroll
            for (int v = 0; v < VPT; ++v)
                if (v0 + v < (long long)V) {
                    ((float*)out)[obase + v * 3 + 0] = ax[v];
                    ((float*)out)[obase + v * 3 + 1] = ay[v];
                    ((float*)out)[obase + v * 3 + 2] = az[v];
                }
        }
    } else {
        if (full) {
            uint4* op = (uint4*)((bf16*)out + obase);
            op[0] = make_uint4(packbf(ax[0], ay[0]), packbf(az[0], ax[1]),
                               packbf(ay[1], az[1]), packbf(ax[2], ay[2]));
            op[1] = make_uint4(packbf(az[2], ax[3]), packbf(ay[3], az[3]),
                               packbf(ax[4], ay[4]), packbf(az[4], ax[5]));
            op[2] = make_uint4(packbf(ay[5], az[5]), packbf(ax[6], ay[6]),
                               packbf(az[6], ax[7]), packbf(ay[7], az[7]));
        } else {
#pragma unroll
            for (int v = 0; v < VPT; ++v)
                if (v0 + v < (long long)V) {
                    st<BF>(out, obase + v * 3 + 0, ax[v]);
                    st<BF>(out, obase + v * 3 + 1, ay[v]);
                    st<BF>(out, obase + v * 3 + 2, az[v]);
                }
        }
    }
}

__global__ void __launch_bounds__(256)
__attribute__((amdgpu_waves_per_eu(2, 4)))
lbs_all(
    const void* __restrict__ verts,
    const void* __restrict__ joints,
    const void* __restrict__ weights,
    const void* __restrict__ disp,
    const void* __restrict__ rdis,
    PosePtrs pp,
    void* __restrict__ out,
    int V)
{
    __shared__ __align__(16) float sA[P_CNT * J_CNT * 12];   // 17664 B
    __shared__ __align__(16) float sW[J_CNT * WSTR];         // 12144 B
    __shared__ float sPose[11 * P_CNT * 3];                  // 2112 B
    __shared__ float sSh[P_CNT * 3];
    __shared__ int   sFlag;

    if (threadIdx.x == 0) {
        const float* wf = (const float*)weights;
        const bf16*  wb = (const bf16*)weights;
        bool ok_f = true, ok_b = true;
        for (int r = 0; r < 4; ++r) {
            float sf = 0.f, sb = 0.f;
            for (int j = 0; j < J_CNT; ++j) {
                sf += wf[r * J_CNT + j];
                sb += __bfloat162float(wb[r * J_CNT + j]);
            }
            if (!(fabsf(sf - 1.f) < 0.02f)) ok_f = false;   // NaN-safe
            if (!(fabsf(sb - 1.f) < 0.10f)) ok_b = false;
        }
        sFlag = (!ok_f && ok_b) ? 1 : 0;
    }
    __syncthreads();
    if (sFlag)
        run<true >(verts, joints, weights, disp, rdis, pp, out, V, sA, sW, sPose, sSh);
    else
        run<false>(verts, joints, weights, disp, rdis, pp, out, V, sA, sW, sPose, sSh);
}

extern "C" void kernel_launch(void* const* d_in, const int* in_sizes, int n_in,
                              void* d_out, int out_size, void* d_ws, size_t ws_size,
                              hipStream_t stream) {
    const void* verts   = d_in[0];  // (1,V,3)
    const void* joints  = d_in[1];  // (1,23,3)
    const void* weights = d_in[2];  // (V,23)
    const void* disp    = d_in[3];  // (16,1,3)
    const void* rdis    = d_in[4];  // (16,3)
    PosePtrs pp;
    for (int i = 0; i < 11; ++i) pp.p[i] = d_in[5 + i];

    int V = in_sizes[0] / 3;  // 500000
    int G = (V + VB - 1) / VB;
    lbs_all<<<G, 256, 0, stream>>>(verts, joints, weights, disp, rdis, pp, d_out, V);
}

// Round 5
// 269.335 us; speedup vs baseline: 2.9236x; 1.0693x over previous
//
#include <hip/hip_runtime.h>
#include <hip/hip_bf16.h>

typedef __hip_bfloat16 bf16;

#define P_CNT 16
#define J_CNT 23
#define VB    256          // verts per block, 1 vert/thread

struct PosePtrs { const void* p[11]; };

__device__ const int   c_par[J_CNT]  = {-1,0,1,1,3,4,5,4,7,4,9,1,11,12,13,12,15,12,17,0,19,0,21};
__device__ const int   c_slot[J_CNT] = {0,-1,-1,1,2,3,-1,4,-1,5,-1,6,7,8,-1,9,-1,10,-1,-1,-1,-1,-1};
__device__ const float c_scale[11]   = {
    0.7853981633974483f, 1.5707963267948966f, 1.5707963267948966f, 0.7853981633974483f,
    0.7853981633974483f, 0.7853981633974483f, 1.5707963267948966f, 1.5707963267948966f,
    0.7853981633974483f, 0.7853981633974483f, 0.7853981633974483f};

template <bool BF>
__device__ __forceinline__ float ld(const void* p, long long i) {
    if (BF) return __bfloat162float(((const bf16*)p)[i]);
    return ((const float*)p)[i];
}
template <bool BF>
__device__ __forceinline__ void st(void* p, long long i, float v) {
    if (BF) ((bf16*)p)[i] = __float2bfloat16(v);
    else    ((float*)p)[i] = v;
}

template <bool BF>
__device__ __forceinline__ void run(const void* __restrict__ verts,
                                    const void* __restrict__ joints,
                                    const void* __restrict__ weights,
                                    const void* __restrict__ disp,
                                    const void* __restrict__ rdis,
                                    const PosePtrs pp,
                                    void* __restrict__ out, int V,
                                    float* __restrict__ sA,
                                    float* __restrict__ sPose,
                                    float* __restrict__ sSh)
{
    const int t = threadIdx.x;
    const long long vb = (long long)blockIdx.x * VB;

    // ---- stage pose params -> LDS (compile-time slot index: no kernarg
    //      dynamic indexing -> no scratch) ----
#pragma unroll
    for (int s = 0; s < 11; ++s) {
        if (t < P_CNT * 3) sPose[s * (P_CNT * 3) + t] = ld<BF>(pp.p[s], t);
    }
    if (t < P_CNT) {
#pragma unroll
        for (int cc = 0; cc < 3; ++cc)
            sSh[t * 3 + cc] = ld<BF>(rdis, t * 3 + cc) + 3.f * tanhf(ld<BF>(disp, t * 3 + cc));
    }
    __syncthreads();

    // ---- phase 1: per-(p,j) local transforms T=[R|t] by ALL threads ----
#pragma unroll 1
    for (int idx = t; idx < P_CNT * J_CNT; idx += 256) {
        int pq = idx / J_CNT, j = idx - pq * J_CNT;
        float rx = 0.f, ry = 0.f, rz = 0.f;
        int s = c_slot[j];
        if (s >= 0) {
            float sc = c_scale[s];
            rx = sc * tanhf(sPose[s * (P_CNT * 3) + pq * 3 + 0]);
            ry = sc * tanhf(sPose[s * (P_CNT * 3) + pq * 3 + 1]);
            rz = sc * tanhf(sPose[s * (P_CNT * 3) + pq * 3 + 2]);
        }
        float ang = sqrtf(rx * rx + ry * ry + rz * rz + 1e-16f);
        float sn = sinf(ang), cs = cosf(ang);
        float C = 1.f - cs, inva = 1.f / ang;
        float x = rx * inva, y = ry * inva, z = rz * inva;
        float t0 = ld<BF>(joints, j * 3 + 0);
        float t1 = ld<BF>(joints, j * 3 + 1);
        float t2 = ld<BF>(joints, j * 3 + 2);
        if (j != 0) {
            int q = c_par[j];
            t0 -= ld<BF>(joints, q * 3 + 0);
            t1 -= ld<BF>(joints, q * 3 + 1);
            t2 -= ld<BF>(joints, q * 3 + 2);
        }
        float* Ar = sA + idx * 12;
        Ar[0]  = 1.f - C * (y * y + z * z); Ar[1]  = -sn * z + C * x * y;       Ar[2]  = sn * y + C * x * z;        Ar[3]  = t0;
        Ar[4]  = sn * z + C * x * y;        Ar[5]  = 1.f - C * (x * x + z * z); Ar[6]  = -sn * x + C * y * z;       Ar[7]  = t1;
        Ar[8]  = -sn * y + C * x * z;       Ar[9]  = sn * x + C * y * z;        Ar[10] = 1.f - C * (x * x + y * y); Ar[11] = t2;
    }
    __syncthreads();

    // ---- phase 2: chain composition in-place (16 lanes, own pose only) ----
    if (t < P_CNT) {
        float* Gp = sA + t * (J_CNT * 12);
#pragma unroll 1
        for (int j = 1; j < J_CNT; ++j) {
            const float* Gq = Gp + c_par[j] * 12;
            float* Tj = Gp + j * 12;
            float4 gq0 = *(const float4*)(Gq + 0);
            float4 gq1 = *(const float4*)(Gq + 4);
            float4 gq2 = *(const float4*)(Gq + 8);
            float4 r0 = *(const float4*)(Tj + 0);
            float4 r1 = *(const float4*)(Tj + 4);
            float4 r2 = *(const float4*)(Tj + 8);
            float4 o0, o1, o2;
            o0.x = gq0.x*r0.x + gq0.y*r1.x + gq0.z*r2.x;
            o0.y = gq0.x*r0.y + gq0.y*r1.y + gq0.z*r2.y;
            o0.z = gq0.x*r0.z + gq0.y*r1.z + gq0.z*r2.z;
            o0.w = gq0.x*r0.w + gq0.y*r1.w + gq0.z*r2.w + gq0.w;
            o1.x = gq1.x*r0.x + gq1.y*r1.x + gq1.z*r2.x;
            o1.y = gq1.x*r0.y + gq1.y*r1.y + gq1.z*r2.y;
            o1.z = gq1.x*r0.z + gq1.y*r1.z + gq1.z*r2.z;
            o1.w = gq1.x*r0.w + gq1.y*r1.w + gq1.z*r2.w + gq1.w;
            o2.x = gq2.x*r0.x + gq2.y*r1.x + gq2.z*r2.x;
            o2.y = gq2.x*r0.y + gq2.y*r1.y + gq2.z*r2.y;
            o2.z = gq2.x*r0.z + gq2.y*r1.z + gq2.z*r2.z;
            o2.w = gq2.x*r0.w + gq2.y*r1.w + gq2.z*r2.w + gq2.w;
            *(float4*)(Tj + 0) = o0;
            *(float4*)(Tj + 4) = o1;
            *(float4*)(Tj + 8) = o2;
        }
    }
    __syncthreads();

    // ---- phase 3: G -> A in place (t' = t - R*j); block 0 writes out1 ----
    {
        const long long pv3 = (long long)P_CNT * V * 3;
#pragma unroll 1
        for (int idx = t; idx < P_CNT * J_CNT; idx += 256) {
            int pq = idx / J_CNT, j = idx - pq * J_CNT;
            float jx = ld<BF>(joints, j * 3 + 0);
            float jy = ld<BF>(joints, j * 3 + 1);
            float jz = ld<BF>(joints, j * 3 + 2);
            float* Ar = sA + idx * 12;
            float g03 = Ar[3], g13 = Ar[7], g23 = Ar[11];
            Ar[3]  = g03 - (Ar[0] * jx + Ar[1] * jy + Ar[2]  * jz);
            Ar[7]  = g13 - (Ar[4] * jx + Ar[5] * jy + Ar[6]  * jz);
            Ar[11] = g23 - (Ar[8] * jx + Ar[9] * jy + Ar[10] * jz);
            if (blockIdx.x == 0) {
                void* out1 = BF ? (void*)((bf16*)out + pv3) : (void*)((float*)out + pv3);
                st<BF>(out1, (long long)idx * 3 + 0, g03 + sSh[pq * 3 + 0]);
                st<BF>(out1, (long long)idx * 3 + 1, g13 + sSh[pq * 3 + 1]);
                st<BF>(out1, (long long)idx * 3 + 2, g23 + sSh[pq * 3 + 2]);
            }
        }
    }
    __syncthreads();

    // ---- main: 1 vertex/thread, w[23] in VGPRs, uniform A broadcast reads ----
    const long long v = vb + t;
    if (v >= (long long)V) return;

    float w[J_CNT];
    const long long wbase = v * J_CNT;
#pragma unroll
    for (int j = 0; j < J_CNT; ++j) w[j] = ld<BF>(weights, wbase + j);
    float x = ld<BF>(verts, v * 3 + 0);
    float y = ld<BF>(verts, v * 3 + 1);
    float z = ld<BF>(verts, v * 3 + 2);

    const float4* A4 = (const float4*)sA;
    for (int p = 0; p < P_CNT; ++p) {
        const float4* Ap = A4 + p * (J_CNT * 3);
        float4 t0 = make_float4(0.f, 0.f, 0.f, 0.f);
        float4 t1 = make_float4(0.f, 0.f, 0.f, 0.f);
        float4 t2 = make_float4(0.f, 0.f, 0.f, 0.f);
#pragma unroll
        for (int j = 0; j < J_CNT; ++j) {
            float wj = w[j];
            float4 a0 = Ap[j * 3 + 0], a1 = Ap[j * 3 + 1], a2 = Ap[j * 3 + 2];
            t0.x = fmaf(wj, a0.x, t0.x); t0.y = fmaf(wj, a0.y, t0.y);
            t0.z = fmaf(wj, a0.z, t0.z); t0.w = fmaf(wj, a0.w, t0.w);
            t1.x = fmaf(wj, a1.x, t1.x); t1.y = fmaf(wj, a1.y, t1.y);
            t1.z = fmaf(wj, a1.z, t1.z); t1.w = fmaf(wj, a1.w, t1.w);
            t2.x = fmaf(wj, a2.x, t2.x); t2.y = fmaf(wj, a2.y, t2.y);
            t2.z = fmaf(wj, a2.z, t2.z); t2.w = fmaf(wj, a2.w, t2.w);
        }
        float ox = fmaf(t0.x, x, fmaf(t0.y, y, fmaf(t0.z, z, t0.w))) + sSh[p * 3 + 0];
        float oy = fmaf(t1.x, x, fmaf(t1.y, y, fmaf(t1.z, z, t1.w))) + sSh[p * 3 + 1];
        float oz = fmaf(t2.x, x, fmaf(t2.y, y, fmaf(t2.z, z, t2.w))) + sSh[p * 3 + 2];
        long long base = ((long long)p * V + v) * 3;
        st<BF>(out, base + 0, ox);
        st<BF>(out, base + 1, oy);
        st<BF>(out, base + 2, oz);
    }
}

__global__ void __launch_bounds__(256) lbs_all(
    const void* __restrict__ verts,
    const void* __restrict__ joints,
    const void* __restrict__ weights,
    const void* __restrict__ disp,
    const void* __restrict__ rdis,
    PosePtrs pp,
    void* __restrict__ out,
    int V)
{
    __shared__ __align__(16) float sA[P_CNT * J_CNT * 12];   // 17664 B
    __shared__ float sPose[11 * P_CNT * 3];                  // 2112 B
    __shared__ float sSh[P_CNT * 3];
    __shared__ int   sFlag;

    if (threadIdx.x == 0) {
        // dtype detect via sum(weights row r)==1 invariant, rows 0..3
        const float* wf = (const float*)weights;
        const bf16*  wb = (const bf16*)weights;
        bool ok_f = true, ok_b = true;
        for (int r = 0; r < 4; ++r) {
            float sf = 0.f, sb = 0.f;
            for (int j = 0; j < J_CNT; ++j) {
                sf += wf[r * J_CNT + j];
                sb += __bfloat162float(wb[r * J_CNT + j]);
            }
            if (!(fabsf(sf - 1.f) < 0.02f)) ok_f = false;   // NaN-safe
            if (!(fabsf(sb - 1.f) < 0.10f)) ok_b = false;
        }
        sFlag = (!ok_f && ok_b) ? 1 : 0;
    }
    __syncthreads();
    if (sFlag)
        run<true >(verts, joints, weights, disp, rdis, pp, out, V, sA, sPose, sSh);
    else
        run<false>(verts, joints, weights, disp, rdis, pp, out, V, sA, sPose, sSh);
}

extern "C" void kernel_launch(void* const* d_in, const int* in_sizes, int n_in,
                              void* d_out, int out_size, void* d_ws, size_t ws_size,
                              hipStream_t stream) {
    const void* verts   = d_in[0];  // (1,V,3)
    const void* joints  = d_in[1];  // (1,23,3)
    const void* weights = d_in[2];  // (V,23)
    const void* disp    = d_in[3];  // (16,1,3)
    const void* rdis    = d_in[4];  // (16,3)
    PosePtrs pp;
    for (int i = 0; i < 11; ++i) pp.p[i] = d_in[5 + i];

    int V = in_sizes[0] / 3;  // 500000
    int G = (V + VB - 1) / VB;
    lbs_all<<<G, 256, 0, stream>>>(verts, joints, weights, disp, rdis, pp, d_out, V);
}